// Round 13
// baseline (429.120 us; speedup 1.0000x reference)
//
#include <hip/hip_runtime.h>
#include <hip/hip_cooperative_groups.h>

namespace cg = cooperative_groups;

#define H 128
#define HC 64
#define NOUT 10

static constexpr int kN = 100000;
static constexpr int kE = 600000;
static constexpr int kG = 1000;

typedef __attribute__((ext_vector_type(8))) short short8v;
typedef __attribute__((ext_vector_type(4))) float f32x4;

__device__ __forceinline__ float4 ld4(const float* p) { return *(const float4*)p; }

// fp32 -> bf16 round-to-nearest-even
__device__ __forceinline__ unsigned f2bf(float f) {
    unsigned u = __float_as_uint(f);
    return (u + 0x7fffu + ((u >> 16) & 1u)) >> 16;
}
__device__ __forceinline__ unsigned f2bf2(float a, float b) {
    return f2bf(a) | (f2bf(b) << 16);
}
__device__ __forceinline__ void unpack_add8(uint4 u, float* a) {
    a[0] += __uint_as_float(u.x << 16); a[1] += __uint_as_float(u.x & 0xFFFF0000u);
    a[2] += __uint_as_float(u.y << 16); a[3] += __uint_as_float(u.y & 0xFFFF0000u);
    a[4] += __uint_as_float(u.z << 16); a[5] += __uint_as_float(u.z & 0xFFFF0000u);
    a[6] += __uint_as_float(u.w << 16); a[7] += __uint_as_float(u.w & 0xFFFF0000u);
}

// LDS tile swizzle: ushort-index XOR mask for row rl (flips granule bits 3-6)
__device__ __forceinline__ int swzmask(int rl) { return (rl & 15) << 3; }

// ---------------- cooperative: setup + full CSR build in ONE kernel ----------------
// 512 blocks x 256 threads (2 blocks/CU -> co-resident; grid.sync valid)
__global__ void k_csr(int* __restrict__ deg,
                      const float* __restrict__ Wa, const float* __restrict__ Wb,
                      const float* __restrict__ Wc, unsigned short* __restrict__ wpk,
                      const int* __restrict__ batch, int* __restrict__ browptr,
                      const float* __restrict__ Wf2, float* __restrict__ Wf2T,
                      const float* __restrict__ Wc1, float* __restrict__ Wc1T,
                      const int* __restrict__ src, const int* __restrict__ dstp,
                      int* __restrict__ rowptr, int* __restrict__ partial,
                      int* __restrict__ eidx) {
    cg::grid_group grid = cg::this_grid();
    const int t = threadIdx.x, bid = blockIdx.x;
    const int gt = bid * 256 + t;           // 0..131071
    const int GT = 512 * 256;

    __shared__ int red[256];
    __shared__ int sh[256];

    // ---- phase 1: setup tasks (zero deg, wpack x3, bsearch, W transposes) ----
    if (gt < 25000) {                       // zero deg: 100000 ints = 25000 int4
        ((int4*)deg)[gt] = make_int4(0, 0, 0, 0);
    } else if (gt < 31144) {                // W repack x3
        int gt2 = gt - 25000;
        int m = gt2 >> 11, tt = gt2 & 2047;
        const float* W = (m == 0) ? Wa : (m == 1) ? Wb : Wc;
        int lane = tt & 63, fc = tt >> 6;
        int kb = fc >> 3, c16 = fc & 7;
        int col = c16 * 16 + (lane & 15);
        int k0 = kb * 32 + (lane >> 4) * 8;
        unsigned r[4];
#pragma unroll
        for (int p = 0; p < 4; ++p) {
            float a = W[(size_t)(k0 + 2 * p) * H + col];
            float b = W[(size_t)(k0 + 2 * p + 1) * H + col];
            r[p] = f2bf2(a, b);
        }
        *(uint4*)(wpk + (size_t)m * 16384 + (size_t)tt * 8) = make_uint4(r[0], r[1], r[2], r[3]);
    } else if (gt < 32145) {                // browptr via binary search
        int g = gt - 31144;
        int lo = 0, hi = kN;
        while (lo < hi) {
            int mid = (lo + hi) >> 1;
            if (batch[mid] < g) lo = mid + 1; else hi = mid;
        }
        browptr[g] = lo;
    } else if (gt < 36241) {                // Wf2T[col][j] = Wf2[j][col]
        int id = gt - 32145;
        int col = id >> 5, j4 = id & 31;
        float4 v;
        v.x = Wf2[(j4 * 4 + 0) * H + col];
        v.y = Wf2[(j4 * 4 + 1) * H + col];
        v.z = Wf2[(j4 * 4 + 2) * H + col];
        v.w = Wf2[(j4 * 4 + 3) * H + col];
        ((float4*)Wf2T)[col * 32 + j4] = v;
    } else if (gt < 38289) {                // Wc1T[t64][j] = Wc1[j][t64]
        int id = gt - 36241;
        int t64 = id >> 5, j4 = id & 31;
        float4 v;
        v.x = Wc1[(j4 * 4 + 0) * HC + t64];
        v.y = Wc1[(j4 * 4 + 1) * HC + t64];
        v.z = Wc1[(j4 * 4 + 2) * HC + t64];
        v.w = Wc1[(j4 * 4 + 3) * HC + t64];
        ((float4*)Wc1T)[t64 * 32 + j4] = v;
    }
    grid.sync();

    // ---- phase 2: degree histogram ----
    for (int e = gt; e < kE; e += GT) atomicAdd(&deg[dstp[e]], 1);
    grid.sync();

    // ---- phase 3a: per-block sums (1 element/thread) ----
    const int i = gt;
    int v = (i < kN) ? deg[i] : 0;
    red[t] = v;         // keep values for the scan
    sh[t] = v;
    __syncthreads();
    for (int off = 128; off; off >>= 1) {
        if (t < off) sh[t] += sh[t + off];
        __syncthreads();
    }
    if (t == 0) partial[bid] = sh[0];
    grid.sync();

    // ---- phase 3b: self-base + in-block inclusive scan; write rowptr + cursor ----
    int acc0 = ((t < bid) ? partial[t] : 0) + ((t + 256 < bid) ? partial[t + 256] : 0);
    __syncthreads();    // red[] reads in scan below must not race the sh reduce
    sh[t] = acc0;
    __syncthreads();
    for (int off = 128; off; off >>= 1) {
        if (t < off) sh[t] += sh[t + off];
        __syncthreads();
    }
    const int bbase = sh[0];
    __syncthreads();
    for (int off = 1; off < 256; off <<= 1) {
        int u = (t >= off) ? red[t - off] : 0;
        __syncthreads();
        red[t] += u;
        __syncthreads();
    }
    const int incl = red[t];
    const int tbase = bbase + incl - v;
    if (i < kN) { rowptr[i] = tbase; deg[i] = tbase; }   // deg doubles as scatter cursor
    if (bid == 511 && t == 255) rowptr[kN] = bbase + incl;  // = E
    grid.sync();

    // ---- phase 4: scatter edges into dst-buckets ----
    for (int e = gt; e < kE; e += GT) {
        int slot = atomicAdd(&deg[dstp[e]], 1);
        eidx[slot] = src[e];
    }
}

// ---------------- gather + self-add (16 lanes/node, 4-edge MLP batching) ----------------
__global__ void k_gather_add(const int* __restrict__ rowptr, const int* __restrict__ eidx,
                             const unsigned short* __restrict__ x, unsigned short* __restrict__ out,
                             int nN) {
    int idx = blockIdx.x * blockDim.x + threadIdx.x;
    int i = idx >> 4, q = idx & 15;  // q: 8-elem chunk
    if (i >= nN) return;
    const int off = q * 8;
    float a[8] = {0, 0, 0, 0, 0, 0, 0, 0};
    unpack_add8(*(const uint4*)(x + (size_t)i * H + off), a);
    int j0 = rowptr[i], j1 = rowptr[i + 1];
    int j = j0;
    for (; j + 4 <= j1; j += 4) {
        int e0 = eidx[j], e1 = eidx[j + 1], e2 = eidx[j + 2], e3 = eidx[j + 3];
        uint4 u0 = *(const uint4*)(x + (size_t)e0 * H + off);
        uint4 u1 = *(const uint4*)(x + (size_t)e1 * H + off);
        uint4 u2 = *(const uint4*)(x + (size_t)e2 * H + off);
        uint4 u3 = *(const uint4*)(x + (size_t)e3 * H + off);
        unpack_add8(u0, a); unpack_add8(u1, a);
        unpack_add8(u2, a); unpack_add8(u3, a);
    }
    for (; j < j1; ++j) {
        int s = eidx[j];
        unpack_add8(*(const uint4*)(x + (size_t)s * H + off), a);
    }
    *(uint4*)(out + (size_t)i * H + off) =
        make_uint4(f2bf2(a[0], a[1]), f2bf2(a[2], a[3]), f2bf2(a[4], a[5]), f2bf2(a[6], a[7]));
}

// ---------------- fused GIN1: pos-gather (2-lane split, 2-edge MLP) + hA1 -> MFMA -> BN -> x1 ----------------
__global__ __launch_bounds__(256) void k_gin1(
    const float* __restrict__ pos,
    const int* __restrict__ rowptr, const int* __restrict__ eidx,
    const float* __restrict__ W1a, const float* __restrict__ b1a,
    const short8v* __restrict__ wpk, const float* __restrict__ bias,
    const float* __restrict__ bn_g, const float* __restrict__ bn_b,
    const float* __restrict__ bn_rm, const float* __restrict__ bn_rv,
    unsigned short* __restrict__ out, int nN) {
    __shared__ unsigned short As[H * H];  // 32 KB swizzled bf16 tile
    __shared__ float sB[H], sS[H], sH2[H];
    const int t = threadIdx.x;

    if (t < H) {
        sB[t] = bias[t];
        float s = bn_g[t] * rsqrtf(bn_rv[t] + 1e-5f);
        sS[t] = s;
        sH2[t] = bn_b[t] - bn_rm[t] * s;
    }

    // phase 0: gather pos (edges split across the 2 lanes of each row, 2-edge batches) + hA1 tile
    {
        const int rl = t >> 1, half = t & 1;
        const int ic = min(blockIdx.x * 128 + rl, nN - 1);
        float2 p = ((const float2*)pos)[ic];
        float x0 = half ? 0.f : p.x;   // self counted once
        float x1 = half ? 0.f : p.y;
        int j0 = rowptr[ic], j1 = rowptr[ic + 1];
        int j = j0 + half;
        for (; j + 2 < j1; j += 4) {   // this lane's edges: j, j+2 (both < j1)
            int e0 = eidx[j], e1 = eidx[j + 2];
            float2 q0 = ((const float2*)pos)[e0];
            float2 q1 = ((const float2*)pos)[e1];
            x0 += q0.x + q1.x; x1 += q0.y + q1.y;
        }
        for (; j < j1; j += 2) {
            float2 q = ((const float2*)pos)[eidx[j]];
            x0 += q.x; x1 += q.y;
        }
        x0 += __shfl_xor(x0, 1);
        x1 += __shfl_xor(x1, 1);

        const int mask = swzmask(rl);
#pragma unroll
        for (int c4 = 0; c4 < 16; ++c4) {
            int c = half * 64 + c4 * 4;
            float4 w0 = ld4(&W1a[c]);
            float4 w1 = ld4(&W1a[H + c]);
            float4 bb = ld4(&b1a[c]);
            float r0 = fmaxf(x0 * w0.x + x1 * w1.x + bb.x, 0.f);
            float r1 = fmaxf(x0 * w0.y + x1 * w1.y + bb.y, 0.f);
            float r2 = fmaxf(x0 * w0.z + x1 * w1.z + bb.z, 0.f);
            float r3 = fmaxf(x0 * w0.w + x1 * w1.w + bb.w, 0.f);
            int idx = rl * H + c;
            *(uint2*)(As + (idx ^ mask)) = make_uint2(f2bf2(r0, r1), f2bf2(r2, r3));
        }
    }
    __syncthreads();

    const int lane = t & 63;
    const int wave = t >> 6;
    const int rowbase = blockIdx.x * 128 + wave * 32;
    const int lrow = lane & 15;
    const int lhi = lane >> 4;

    f32x4 acc[2][8];
#pragma unroll
    for (int rr = 0; rr < 2; ++rr)
#pragma unroll
        for (int c = 0; c < 8; ++c) acc[rr][c] = (f32x4){0.f, 0.f, 0.f, 0.f};

#pragma unroll
    for (int kb = 0; kb < 4; ++kb) {
        short8v xf[2];
#pragma unroll
        for (int rr = 0; rr < 2; ++rr) {
            int rl = wave * 32 + rr * 16 + lrow;
            int idx = rl * H + kb * 32 + lhi * 8;
            xf[rr] = *(const short8v*)(As + (idx ^ swzmask(rl)));
        }
#pragma unroll
        for (int c16 = 0; c16 < 8; ++c16) {
            short8v wf = wpk[(kb * 8 + c16) * 64 + lane];
            acc[0][c16] = __builtin_amdgcn_mfma_f32_16x16x32_bf16(wf, xf[0], acc[0][c16], 0, 0, 0);
            acc[1][c16] = __builtin_amdgcn_mfma_f32_16x16x32_bf16(wf, xf[1], acc[1][c16], 0, 0, 0);
        }
    }

#pragma unroll
    for (int c16 = 0; c16 < 8; ++c16) {
        const int c0 = c16 * 16 + lhi * 4;
        float b0 = sB[c0], b1 = sB[c0 + 1], b2 = sB[c0 + 2], b3 = sB[c0 + 3];
        float s0 = sS[c0], s1 = sS[c0 + 1], s2 = sS[c0 + 2], s3 = sS[c0 + 3];
        float h0 = sH2[c0], h1 = sH2[c0 + 1], h2 = sH2[c0 + 2], h3 = sH2[c0 + 3];
#pragma unroll
        for (int rr = 0; rr < 2; ++rr) {
            int row = rowbase + rr * 16 + lrow;
            if (row >= nN) continue;
            float v0 = fmaxf(acc[rr][c16][0] + b0, 0.f) * s0 + h0;
            float v1 = fmaxf(acc[rr][c16][1] + b1, 0.f) * s1 + h1;
            float v2 = fmaxf(acc[rr][c16][2] + b2, 0.f) * s2 + h2;
            float v3 = fmaxf(acc[rr][c16][3] + b3, 0.f) * s3 + h3;
            *(uint2*)(out + (size_t)row * H + c0) = make_uint2(f2bf2(v0, v1), f2bf2(v2, v3));
        }
    }
}

// ---------------- fused GIN2: mmA (s2 from global, relu) -> LDS -> mmB -> BN -> x2 (in-place) ----------------
__global__ __launch_bounds__(256) void k_gin2(
    const unsigned short* __restrict__ xin, const short8v* __restrict__ wpA,
    const float* __restrict__ biasA, const short8v* __restrict__ wpB,
    const float* __restrict__ biasB,
    const float* __restrict__ bn_g, const float* __restrict__ bn_b,
    const float* __restrict__ bn_rm, const float* __restrict__ bn_rv,
    unsigned short* __restrict__ out, int nN) {
    __shared__ unsigned short As[H * H];  // 32 KB swizzled bf16 tile (hA2)
    __shared__ float sBa[H], sBb[H], sS[H], sH2[H];
    const int t = threadIdx.x;

    if (t < H) {
        sBa[t] = biasA[t];
        sBb[t] = biasB[t];
        float s = bn_g[t] * rsqrtf(bn_rv[t] + 1e-5f);
        sS[t] = s;
        sH2[t] = bn_b[t] - bn_rm[t] * s;
    }
    __syncthreads();

    const int lane = t & 63;
    const int wave = t >> 6;
    const int rowbase = blockIdx.x * 128 + wave * 32;
    const int lrow = lane & 15;
    const int lhi = lane >> 4;

    f32x4 acc[2][8];
#pragma unroll
    for (int rr = 0; rr < 2; ++rr)
#pragma unroll
        for (int c = 0; c < 8; ++c) acc[rr][c] = (f32x4){0.f, 0.f, 0.f, 0.f};

    // phase 1: hA2 = relu(s2 @ W2a + b2a), xf from global
#pragma unroll
    for (int kb = 0; kb < 4; ++kb) {
        short8v xf[2];
#pragma unroll
        for (int rr = 0; rr < 2; ++rr) {
            int row = rowbase + rr * 16 + lrow;
            row = row < nN ? row : nN - 1;
            xf[rr] = *(const short8v*)(xin + (size_t)row * H + kb * 32 + lhi * 8);
        }
#pragma unroll
        for (int c16 = 0; c16 < 8; ++c16) {
            short8v wf = wpA[(kb * 8 + c16) * 64 + lane];
            acc[0][c16] = __builtin_amdgcn_mfma_f32_16x16x32_bf16(wf, xf[0], acc[0][c16], 0, 0, 0);
            acc[1][c16] = __builtin_amdgcn_mfma_f32_16x16x32_bf16(wf, xf[1], acc[1][c16], 0, 0, 0);
        }
    }

    // epilogue 1 -> swizzled LDS (hA2)
#pragma unroll
    for (int c16 = 0; c16 < 8; ++c16) {
        const int c0 = c16 * 16 + lhi * 4;
        float b0 = sBa[c0], b1 = sBa[c0 + 1], b2 = sBa[c0 + 2], b3 = sBa[c0 + 3];
#pragma unroll
        for (int rr = 0; rr < 2; ++rr) {
            int rl = wave * 32 + rr * 16 + lrow;
            float v0 = fmaxf(acc[rr][c16][0] + b0, 0.f);
            float v1 = fmaxf(acc[rr][c16][1] + b1, 0.f);
            float v2 = fmaxf(acc[rr][c16][2] + b2, 0.f);
            float v3 = fmaxf(acc[rr][c16][3] + b3, 0.f);
            int idx = rl * H + c0;
            *(uint2*)(As + (idx ^ swzmask(rl))) = make_uint2(f2bf2(v0, v1), f2bf2(v2, v3));
        }
    }
    __syncthreads();

    // phase 2: x2 = BN(relu(hA2 @ W2b + b2b)), xf from LDS
#pragma unroll
    for (int rr = 0; rr < 2; ++rr)
#pragma unroll
        for (int c = 0; c < 8; ++c) acc[rr][c] = (f32x4){0.f, 0.f, 0.f, 0.f};

#pragma unroll
    for (int kb = 0; kb < 4; ++kb) {
        short8v xf[2];
#pragma unroll
        for (int rr = 0; rr < 2; ++rr) {
            int rl = wave * 32 + rr * 16 + lrow;
            int idx = rl * H + kb * 32 + lhi * 8;
            xf[rr] = *(const short8v*)(As + (idx ^ swzmask(rl)));
        }
#pragma unroll
        for (int c16 = 0; c16 < 8; ++c16) {
            short8v wf = wpB[(kb * 8 + c16) * 64 + lane];
            acc[0][c16] = __builtin_amdgcn_mfma_f32_16x16x32_bf16(wf, xf[0], acc[0][c16], 0, 0, 0);
            acc[1][c16] = __builtin_amdgcn_mfma_f32_16x16x32_bf16(wf, xf[1], acc[1][c16], 0, 0, 0);
        }
    }

#pragma unroll
    for (int c16 = 0; c16 < 8; ++c16) {
        const int c0 = c16 * 16 + lhi * 4;
        float b0 = sBb[c0], b1 = sBb[c0 + 1], b2 = sBb[c0 + 2], b3 = sBb[c0 + 3];
        float s0 = sS[c0], s1 = sS[c0 + 1], s2 = sS[c0 + 2], s3 = sS[c0 + 3];
        float h0 = sH2[c0], h1 = sH2[c0 + 1], h2 = sH2[c0 + 2], h3 = sH2[c0 + 3];
#pragma unroll
        for (int rr = 0; rr < 2; ++rr) {
            int row = rowbase + rr * 16 + lrow;
            if (row >= nN) continue;
            float v0 = fmaxf(acc[rr][c16][0] + b0, 0.f) * s0 + h0;
            float v1 = fmaxf(acc[rr][c16][1] + b1, 0.f) * s1 + h1;
            float v2 = fmaxf(acc[rr][c16][2] + b2, 0.f) * s2 + h2;
            float v3 = fmaxf(acc[rr][c16][3] + b3, 0.f) * s3 + h3;
            *(uint2*)(out + (size_t)row * H + c0) = make_uint2(f2bf2(v0, v1), f2bf2(v2, v3));
        }
    }
}

// ---------------- one block per graph (256 thr): pools + x0g/x1g/x2g + classifier ----------------
__global__ __launch_bounds__(256) void k_graph(
    const float* __restrict__ pos,
    const unsigned short* __restrict__ x1, const unsigned short* __restrict__ x2,
    const int* __restrict__ browptr,
    const float* __restrict__ Wf1, const float* __restrict__ bf1,
    const float* __restrict__ f1g, const float* __restrict__ f1b,
    const float* __restrict__ f1rm, const float* __restrict__ f1rv,
    const float* __restrict__ Wf2T, const float* __restrict__ bf2,
    const float* __restrict__ f2g, const float* __restrict__ f2b,
    const float* __restrict__ f2rm, const float* __restrict__ f2rv,
    const float* __restrict__ Wc1T, const float* __restrict__ bc1,
    const float* __restrict__ gc, const float* __restrict__ bec,
    const float* __restrict__ rmc, const float* __restrict__ rvc,
    const float* __restrict__ ap,
    const float* __restrict__ Wc2, const float* __restrict__ bc2,
    float* __restrict__ out) {
    __shared__ float redx[256], redy[256];
    __shared__ float part1[4][16][8], part2[4][16][8];
    __shared__ float row[H];
    __shared__ float hbuf[HC];
    const int gi = blockIdx.x, t = threadIdx.x;
    const int r0 = browptr[gi], r1 = browptr[gi + 1];

    // pos pool (256-way)
    float ax = 0.f, ay = 0.f;
    for (int r = r0 + t; r < r1; r += 256) {
        float2 p = ((const float2*)pos)[r];
        ax += p.x; ay += p.y;
    }
    redx[t] = ax; redy[t] = ay;
    __syncthreads();
    for (int off = 128; off; off >>= 1) {
        if (t < off) { redx[t] += redx[t + off]; redy[t] += redy[t + off]; }
        __syncthreads();
    }
    const float px = redx[0], py = redy[0];

    // x1/x2 pools: 16 col-chunks x 16 row-lanes, uint4 loads
    {
        const int c = t & 15, l = t >> 4;
        float a1[8] = {0, 0, 0, 0, 0, 0, 0, 0};
        float a2[8] = {0, 0, 0, 0, 0, 0, 0, 0};
        for (int r = r0 + l; r < r1; r += 16) {
            unpack_add8(*(const uint4*)(x1 + (size_t)r * H + c * 8), a1);
            unpack_add8(*(const uint4*)(x2 + (size_t)r * H + c * 8), a2);
        }
#pragma unroll
        for (int k = 0; k < 8; ++k) {
            a1[k] += __shfl_xor(a1[k], 16); a1[k] += __shfl_xor(a1[k], 32);
            a2[k] += __shfl_xor(a2[k], 16); a2[k] += __shfl_xor(a2[k], 32);
        }
        const int wv = t >> 6, lane = t & 63;
        if (lane < 16) {
#pragma unroll
            for (int k = 0; k < 8; ++k) {
                part1[wv][lane][k] = a1[k];
                part2[wv][lane][k] = a2[k];
            }
        }
    }
    __syncthreads();

    float x0 = 0.f, p1 = 0.f, p2 = 0.f, s2v = 0.f;
    if (t < H) {
        const int cc = t >> 3, e = t & 7;
        p1 = part1[0][cc][e] + part1[1][cc][e] + part1[2][cc][e] + part1[3][cc][e];
        p2 = part2[0][cc][e] + part2[1][cc][e] + part2[2][cc][e] + part2[3][cc][e];
        float a0 = fmaxf(bf1[t] + px * Wf1[t] + py * Wf1[H + t], 0.f);
        float s1v = f1g[t] * rsqrtf(f1rv[t] + 1e-5f);
        x0 = (a0 - f1rm[t]) * s1v + f1b[t];
        s2v = f2g[t] * rsqrtf(f2rv[t] + 1e-5f);
        row[t] = p1 + x0;
    }
    __syncthreads();

    float x1gv = 0.f;
    if (t < H) {
        float a = bf2[t];
        const float4* wt = (const float4*)(Wf2T + t * H);
#pragma unroll 8
        for (int j4 = 0; j4 < 32; ++j4) {
            float4 w = wt[j4];
            a += row[j4 * 4] * w.x + row[j4 * 4 + 1] * w.y + row[j4 * 4 + 2] * w.z + row[j4 * 4 + 3] * w.w;
        }
        x1gv = (fmaxf(a, 0.f) - f2rm[t]) * s2v + f2b[t];
    }
    __syncthreads();
    if (t < H) row[t] = p2 + x0 + x1gv;
    __syncthreads();

    float x2gv = 0.f;
    if (t < H) {
        float a = bf2[t];
        const float4* wt = (const float4*)(Wf2T + t * H);
#pragma unroll 8
        for (int j4 = 0; j4 < 32; ++j4) {
            float4 w = wt[j4];
            a += row[j4 * 4] * w.x + row[j4 * 4 + 1] * w.y + row[j4 * 4 + 2] * w.z + row[j4 * 4 + 3] * w.w;
        }
        x2gv = (fmaxf(a, 0.f) - f2rm[t]) * s2v + f2b[t];
    }
    __syncthreads();
    if (t < H) row[t] = x2gv;
    __syncthreads();

    if (t < HC) {
        float c = bc1[t];
        const float4* wt = (const float4*)(Wc1T + t * H);
#pragma unroll 8
        for (int j4 = 0; j4 < 32; ++j4) {
            float4 w = wt[j4];
            c += row[j4 * 4] * w.x + row[j4 * 4 + 1] * w.y + row[j4 * 4 + 2] * w.z + row[j4 * 4 + 3] * w.w;
        }
        float sc = gc[t] * rsqrtf(rvc[t] + 1e-5f);
        c = (c - rmc[t]) * sc + bec[t];
        float al = ap[0];
        hbuf[t] = c > 0.f ? c : al * c;
    }
    __syncthreads();
    if (t < NOUT) {
        float c = bc2[t];
        for (int j = 0; j < HC; ++j) c += hbuf[j] * Wc2[j * NOUT + t];
        out[gi * NOUT + t] = c;
    }
}

extern "C" void kernel_launch(void* const* d_in, const int* in_sizes, int n_in,
                              void* d_out, int out_size, void* d_ws, size_t ws_size,
                              hipStream_t stream) {
    const int N = kN, E = kE, G = kG;
    const float* pos = (const float*)d_in[0];
    const int* ei    = (const int*)d_in[1];
    const int* batch = (const int*)d_in[2];
    const float* W1a = (const float*)d_in[3];
    const float* b1a = (const float*)d_in[4];
    const float* W1b = (const float*)d_in[5];
    const float* b1b = (const float*)d_in[6];
    const float* n1g = (const float*)d_in[7];
    const float* n1b = (const float*)d_in[8];
    const float* n1rm = (const float*)d_in[9];
    const float* n1rv = (const float*)d_in[10];
    const float* W2a = (const float*)d_in[11];
    const float* b2a = (const float*)d_in[12];
    const float* W2b = (const float*)d_in[13];
    const float* b2b = (const float*)d_in[14];
    const float* n2g = (const float*)d_in[15];
    const float* n2b = (const float*)d_in[16];
    const float* n2rm = (const float*)d_in[17];
    const float* n2rv = (const float*)d_in[18];
    const float* Wf1 = (const float*)d_in[19];
    const float* bf1 = (const float*)d_in[20];
    const float* f1g = (const float*)d_in[21];
    const float* f1b = (const float*)d_in[22];
    const float* f1rm = (const float*)d_in[23];
    const float* f1rv = (const float*)d_in[24];
    const float* Wf2 = (const float*)d_in[25];
    const float* bf2 = (const float*)d_in[26];
    const float* f2g = (const float*)d_in[27];
    const float* f2b = (const float*)d_in[28];
    const float* f2rm = (const float*)d_in[29];
    const float* f2rv = (const float*)d_in[30];
    const float* Wc1 = (const float*)d_in[31];
    const float* bc1 = (const float*)d_in[32];
    const float* gc  = (const float*)d_in[33];
    const float* bec = (const float*)d_in[34];
    const float* rmc = (const float*)d_in[35];
    const float* rvc = (const float*)d_in[36];
    const float* ap  = (const float*)d_in[37];
    const float* Wc2 = (const float*)d_in[38];
    const float* bc2 = (const float*)d_in[39];
    float* out = (float*)d_out;

    // ---- workspace layout ----
    unsigned short* bx1 = (unsigned short*)d_ws;        // N*H bf16 (x1)
    unsigned short* bx2 = bx1 + (size_t)N * H;          // N*H bf16 (s2 -> x2 in-place)
    unsigned short* wp  = bx2 + (size_t)N * H;          // 3*16384
    float* wf2t  = (float*)(wp + 3 * 16384);            // 16384
    float* wc1t  = wf2t + 16384;                        // 8192
    int* deg     = (int*)(wc1t + 8192);                 // N (reused as cursor)
    int* rowptr  = deg + N;                             // N+1
    int* browptr = rowptr + N + 1;                      // G+1
    int* partial = browptr + G + 1;                     // 1024
    int* eidx    = partial + 1024;                      // E

    const short8v* wp1 = (const short8v*)wp;
    const short8v* wp2 = (const short8v*)(wp + 16384);
    const short8v* wp3 = (const short8v*)(wp + 32768);

    const int* src  = ei;
    const int* dstp = ei + E;

    // 1. cooperative: setup + CSR build (hist, scan, scatter) in ONE kernel
    {
        // mutable locals so we can take addresses
        int* a_deg = deg;
        const float* a_Wa = W1b; const float* a_Wb = W2a; const float* a_Wc = W2b;
        unsigned short* a_wpk = wp;
        const int* a_batch = batch; int* a_browptr = browptr;
        const float* a_Wf2 = Wf2; float* a_wf2t = wf2t;
        const float* a_Wc1 = Wc1; float* a_wc1t = wc1t;
        const int* a_src = src; const int* a_dstp = dstp;
        int* a_rowptr = rowptr; int* a_partial = partial; int* a_eidx = eidx;
        void* params[] = {&a_deg, &a_Wa, &a_Wb, &a_Wc, &a_wpk, &a_batch, &a_browptr,
                          &a_Wf2, &a_wf2t, &a_Wc1, &a_wc1t,
                          &a_src, &a_dstp, &a_rowptr, &a_partial, &a_eidx};
        hipLaunchCooperativeKernel((void*)k_csr, dim3(512), dim3(256), params, 0, stream);
    }

    const int mmBlocks = (N + 127) / 128;

    // 2. GIN1 (pos gather fused, 2-lane edge split + 2-edge MLP)
    k_gin1<<<mmBlocks, 256, 0, stream>>>(pos, rowptr, eidx, W1a, b1a, wp1, b1b,
                                         n1g, n1b, n1rm, n1rv, bx1, N);
    // 3. s2 = x1 + gather(x1) -> bx2 (4-edge MLP batching)
    k_gather_add<<<(N * 16 + 255) / 256, 256, 0, stream>>>(rowptr, eidx, bx1, bx2, N);
    // 4. GIN2 (s2 from global, in-place -> x2)
    k_gin2<<<mmBlocks, 256, 0, stream>>>(bx2, wp2, b2a, wp3, b2b,
                                         n2g, n2b, n2rm, n2rv, bx2, N);
    // 5. all graph-level work + classifier
    k_graph<<<G, 256, 0, stream>>>(pos, bx1, bx2, browptr,
                                   Wf1, bf1, f1g, f1b, f1rm, f1rv,
                                   wf2t, bf2, f2g, f2b, f2rm, f2rv,
                                   wc1t, bc1, gc, bec, rmc, rvc, ap, Wc2, bc2, out);
}

// Round 14
// 205.189 us; speedup vs baseline: 2.0913x; 2.0913x over previous
//
#include <hip/hip_runtime.h>

#define H 128
#define HC 64
#define NOUT 10

static constexpr int kN = 100000;
static constexpr int kE = 600000;
static constexpr int kG = 1000;

typedef __attribute__((ext_vector_type(8))) short short8v;
typedef __attribute__((ext_vector_type(4))) float f32x4;

__device__ __forceinline__ float4 ld4(const float* p) { return *(const float4*)p; }

// fp32 -> bf16 round-to-nearest-even
__device__ __forceinline__ unsigned f2bf(float f) {
    unsigned u = __float_as_uint(f);
    return (u + 0x7fffu + ((u >> 16) & 1u)) >> 16;
}
__device__ __forceinline__ unsigned f2bf2(float a, float b) {
    return f2bf(a) | (f2bf(b) << 16);
}
__device__ __forceinline__ void unpack_add8(uint4 u, float* a) {
    a[0] += __uint_as_float(u.x << 16); a[1] += __uint_as_float(u.x & 0xFFFF0000u);
    a[2] += __uint_as_float(u.y << 16); a[3] += __uint_as_float(u.y & 0xFFFF0000u);
    a[4] += __uint_as_float(u.z << 16); a[5] += __uint_as_float(u.z & 0xFFFF0000u);
    a[6] += __uint_as_float(u.w << 16); a[7] += __uint_as_float(u.w & 0xFFFF0000u);
}

// LDS tile swizzle: ushort-index XOR mask for row rl (flips granule bits 3-6)
__device__ __forceinline__ int swzmask(int rl) { return (rl & 15) << 3; }

// ---------------- setup: zero deg + wpack x3 + bsearch + W transposes ----------------
__global__ void k_setup(int* __restrict__ deg,
                        const float* __restrict__ Wa, const float* __restrict__ Wb,
                        const float* __restrict__ Wc, unsigned short* __restrict__ wpk,
                        const int* __restrict__ batch, int* __restrict__ browptr,
                        const float* __restrict__ Wf2, float* __restrict__ Wf2T,
                        const float* __restrict__ Wc1, float* __restrict__ Wc1T) {
    int gt = blockIdx.x * blockDim.x + threadIdx.x;
    if (gt < 25000) {                       // zero deg: 100000 ints = 25000 int4
        ((int4*)deg)[gt] = make_int4(0, 0, 0, 0);
    } else if (gt < 31144) {                // W repack x3
        int gt2 = gt - 25000;
        int m = gt2 >> 11, t = gt2 & 2047;
        const float* W = (m == 0) ? Wa : (m == 1) ? Wb : Wc;
        int lane = t & 63, fc = t >> 6;
        int kb = fc >> 3, c16 = fc & 7;
        int col = c16 * 16 + (lane & 15);
        int k0 = kb * 32 + (lane >> 4) * 8;
        unsigned r[4];
#pragma unroll
        for (int p = 0; p < 4; ++p) {
            float a = W[(size_t)(k0 + 2 * p) * H + col];
            float b = W[(size_t)(k0 + 2 * p + 1) * H + col];
            r[p] = f2bf2(a, b);
        }
        *(uint4*)(wpk + (size_t)m * 16384 + (size_t)t * 8) = make_uint4(r[0], r[1], r[2], r[3]);
    } else if (gt < 32145) {                // browptr via binary search
        int g = gt - 31144;
        int lo = 0, hi = kN;
        while (lo < hi) {
            int mid = (lo + hi) >> 1;
            if (batch[mid] < g) lo = mid + 1; else hi = mid;
        }
        browptr[g] = lo;
    } else if (gt < 36241) {                // Wf2T[col][j] = Wf2[j][col]  (128x128)
        int id = gt - 32145;                // 4096 threads
        int col = id >> 5, j4 = id & 31;
        float4 v;
        v.x = Wf2[(j4 * 4 + 0) * H + col];
        v.y = Wf2[(j4 * 4 + 1) * H + col];
        v.z = Wf2[(j4 * 4 + 2) * H + col];
        v.w = Wf2[(j4 * 4 + 3) * H + col];
        ((float4*)Wf2T)[col * 32 + j4] = v;
    } else if (gt < 38289) {                // Wc1T[t64][j] = Wc1[j][t64]  (64x128)
        int id = gt - 36241;                // 2048 threads
        int t64 = id >> 5, j4 = id & 31;
        float4 v;
        v.x = Wc1[(j4 * 4 + 0) * HC + t64];
        v.y = Wc1[(j4 * 4 + 1) * HC + t64];
        v.z = Wc1[(j4 * 4 + 2) * HC + t64];
        v.w = Wc1[(j4 * 4 + 3) * HC + t64];
        ((float4*)Wc1T)[t64 * 32 + j4] = v;
    }
}

// ---------------- histogram ----------------
__global__ void k_hist(const int* __restrict__ keys, int* __restrict__ cnt, int n) {
    int i = blockIdx.x * blockDim.x + threadIdx.x;
    if (i < n) atomicAdd(&cnt[keys[i]], 1);
}

// ---------------- scan pass1: block sums (1024 elems/block) ----------------
__global__ void k_scan_p1(const int* __restrict__ in, int* __restrict__ partial, int n) {
    __shared__ int red[256];
    int b = blockIdx.x, t = threadIdx.x;
    int base = b * 1024 + t * 4;
    int s = 0;
#pragma unroll
    for (int k = 0; k < 4; ++k) {
        int j = base + k;
        if (j < n) s += in[j];
    }
    red[t] = s;
    __syncthreads();
    for (int off = 128; off; off >>= 1) {
        if (t < off) red[t] += red[t + off];
        __syncthreads();
    }
    if (t == 0) partial[b] = red[0];
}

// ---------------- scan pass3 (self-basing): exclusive scan + cursor; writes total ----------------
__global__ void k_scan_p3(const int* __restrict__ in, const int* __restrict__ partial,
                          int* __restrict__ out, int* __restrict__ cursor, int n, int nb) {
    __shared__ int bb[256];
    __shared__ int red[256];
    int b = blockIdx.x, t = threadIdx.x;
    bb[t] = (t < b) ? partial[t] : 0;
    __syncthreads();
    for (int off = 128; off; off >>= 1) {
        if (t < off) bb[t] += bb[t + off];
        __syncthreads();
    }
    int bbase = bb[0];

    int base = b * 1024 + t * 4;
    int v[4];
    int s = 0;
#pragma unroll
    for (int k = 0; k < 4; ++k) {
        int j = base + k;
        v[k] = (j < n) ? in[j] : 0;
        s += v[k];
    }
    red[t] = s;
    __syncthreads();
    for (int off = 1; off < 256; off <<= 1) {
        int u = (t >= off) ? red[t - off] : 0;
        __syncthreads();
        red[t] += u;
        __syncthreads();
    }
    int tbase = bbase + red[t] - s;
#pragma unroll
    for (int k = 0; k < 4; ++k) {
        int j = base + k;
        if (j < n) {
            out[j] = tbase;
            if (cursor) cursor[j] = tbase;
            tbase += v[k];
        }
    }
    if (b == nb - 1 && t == 255) out[n] = bbase + red[255];
}

// ---------------- scatter edges into dst-buckets ----------------
__global__ void k_scatter(const int* __restrict__ src, const int* __restrict__ dst,
                          int* __restrict__ cursor, int* __restrict__ eidx, int E) {
    int e = blockIdx.x * blockDim.x + threadIdx.x;
    if (e >= E) return;
    int slot = atomicAdd(&cursor[dst[e]], 1);
    eidx[slot] = src[e];
}

// ---------------- gather + self-add (16 lanes/node, 4/2-edge MLP batching) ----------------
__global__ void k_gather_add(const int* __restrict__ rowptr, const int* __restrict__ eidx,
                             const unsigned short* __restrict__ x, unsigned short* __restrict__ out,
                             int nN) {
    int idx = blockIdx.x * blockDim.x + threadIdx.x;
    int i = idx >> 4, q = idx & 15;  // q: 8-elem chunk
    if (i >= nN) return;
    const int off = q * 8;
    float a[8] = {0, 0, 0, 0, 0, 0, 0, 0};
    unpack_add8(*(const uint4*)(x + (size_t)i * H + off), a);
    int j0 = rowptr[i], j1 = rowptr[i + 1];
    int j = j0;
    for (; j + 4 <= j1; j += 4) {
        int e0 = eidx[j], e1 = eidx[j + 1], e2 = eidx[j + 2], e3 = eidx[j + 3];
        uint4 u0 = *(const uint4*)(x + (size_t)e0 * H + off);
        uint4 u1 = *(const uint4*)(x + (size_t)e1 * H + off);
        uint4 u2 = *(const uint4*)(x + (size_t)e2 * H + off);
        uint4 u3 = *(const uint4*)(x + (size_t)e3 * H + off);
        unpack_add8(u0, a); unpack_add8(u1, a);
        unpack_add8(u2, a); unpack_add8(u3, a);
    }
    if (j + 2 <= j1) {
        int e0 = eidx[j], e1 = eidx[j + 1];
        uint4 u0 = *(const uint4*)(x + (size_t)e0 * H + off);
        uint4 u1 = *(const uint4*)(x + (size_t)e1 * H + off);
        unpack_add8(u0, a); unpack_add8(u1, a);
        j += 2;
    }
    if (j < j1) {
        int s = eidx[j];
        unpack_add8(*(const uint4*)(x + (size_t)s * H + off), a);
    }
    *(uint4*)(out + (size_t)i * H + off) =
        make_uint4(f2bf2(a[0], a[1]), f2bf2(a[2], a[3]), f2bf2(a[4], a[5]), f2bf2(a[6], a[7]));
}

// ---------------- fused GIN1: pos-gather (2-lane split, 2-edge MLP) + hA1 -> MFMA -> BN -> x1 ----------------
__global__ __launch_bounds__(256) void k_gin1(
    const float* __restrict__ pos,
    const int* __restrict__ rowptr, const int* __restrict__ eidx,
    const float* __restrict__ W1a, const float* __restrict__ b1a,
    const short8v* __restrict__ wpk, const float* __restrict__ bias,
    const float* __restrict__ bn_g, const float* __restrict__ bn_b,
    const float* __restrict__ bn_rm, const float* __restrict__ bn_rv,
    unsigned short* __restrict__ out, int nN) {
    __shared__ unsigned short As[H * H];  // 32 KB swizzled bf16 tile
    __shared__ float sB[H], sS[H], sH2[H];
    const int t = threadIdx.x;

    if (t < H) {
        sB[t] = bias[t];
        float s = bn_g[t] * rsqrtf(bn_rv[t] + 1e-5f);
        sS[t] = s;
        sH2[t] = bn_b[t] - bn_rm[t] * s;
    }

    // phase 0: gather pos (edges split across the 2 lanes of each row, 2-edge batches) + hA1 tile
    {
        const int rl = t >> 1, half = t & 1;
        const int ic = min(blockIdx.x * 128 + rl, nN - 1);
        float2 p = ((const float2*)pos)[ic];
        float x0 = half ? 0.f : p.x;   // self counted once
        float x1 = half ? 0.f : p.y;
        int j0 = rowptr[ic], j1 = rowptr[ic + 1];
        int j = j0 + half;
        for (; j + 2 < j1; j += 4) {   // this lane's edges: j, j+2 (both < j1)
            int e0 = eidx[j], e1 = eidx[j + 2];
            float2 q0 = ((const float2*)pos)[e0];
            float2 q1 = ((const float2*)pos)[e1];
            x0 += q0.x + q1.x; x1 += q0.y + q1.y;
        }
        for (; j < j1; j += 2) {
            float2 q = ((const float2*)pos)[eidx[j]];
            x0 += q.x; x1 += q.y;
        }
        x0 += __shfl_xor(x0, 1);
        x1 += __shfl_xor(x1, 1);

        const int mask = swzmask(rl);
#pragma unroll
        for (int c4 = 0; c4 < 16; ++c4) {
            int c = half * 64 + c4 * 4;
            float4 w0 = ld4(&W1a[c]);
            float4 w1 = ld4(&W1a[H + c]);
            float4 bb = ld4(&b1a[c]);
            float r0 = fmaxf(x0 * w0.x + x1 * w1.x + bb.x, 0.f);
            float r1 = fmaxf(x0 * w0.y + x1 * w1.y + bb.y, 0.f);
            float r2 = fmaxf(x0 * w0.z + x1 * w1.z + bb.z, 0.f);
            float r3 = fmaxf(x0 * w0.w + x1 * w1.w + bb.w, 0.f);
            int idx = rl * H + c;
            *(uint2*)(As + (idx ^ mask)) = make_uint2(f2bf2(r0, r1), f2bf2(r2, r3));
        }
    }
    __syncthreads();

    const int lane = t & 63;
    const int wave = t >> 6;
    const int rowbase = blockIdx.x * 128 + wave * 32;
    const int lrow = lane & 15;
    const int lhi = lane >> 4;

    f32x4 acc[2][8];
#pragma unroll
    for (int rr = 0; rr < 2; ++rr)
#pragma unroll
        for (int c = 0; c < 8; ++c) acc[rr][c] = (f32x4){0.f, 0.f, 0.f, 0.f};

#pragma unroll
    for (int kb = 0; kb < 4; ++kb) {
        short8v xf[2];
#pragma unroll
        for (int rr = 0; rr < 2; ++rr) {
            int rl = wave * 32 + rr * 16 + lrow;
            int idx = rl * H + kb * 32 + lhi * 8;
            xf[rr] = *(const short8v*)(As + (idx ^ swzmask(rl)));
        }
#pragma unroll
        for (int c16 = 0; c16 < 8; ++c16) {
            short8v wf = wpk[(kb * 8 + c16) * 64 + lane];
            acc[0][c16] = __builtin_amdgcn_mfma_f32_16x16x32_bf16(wf, xf[0], acc[0][c16], 0, 0, 0);
            acc[1][c16] = __builtin_amdgcn_mfma_f32_16x16x32_bf16(wf, xf[1], acc[1][c16], 0, 0, 0);
        }
    }

#pragma unroll
    for (int c16 = 0; c16 < 8; ++c16) {
        const int c0 = c16 * 16 + lhi * 4;
        float b0 = sB[c0], b1 = sB[c0 + 1], b2 = sB[c0 + 2], b3 = sB[c0 + 3];
        float s0 = sS[c0], s1 = sS[c0 + 1], s2 = sS[c0 + 2], s3 = sS[c0 + 3];
        float h0 = sH2[c0], h1 = sH2[c0 + 1], h2 = sH2[c0 + 2], h3 = sH2[c0 + 3];
#pragma unroll
        for (int rr = 0; rr < 2; ++rr) {
            int row = rowbase + rr * 16 + lrow;
            if (row >= nN) continue;
            float v0 = fmaxf(acc[rr][c16][0] + b0, 0.f) * s0 + h0;
            float v1 = fmaxf(acc[rr][c16][1] + b1, 0.f) * s1 + h1;
            float v2 = fmaxf(acc[rr][c16][2] + b2, 0.f) * s2 + h2;
            float v3 = fmaxf(acc[rr][c16][3] + b3, 0.f) * s3 + h3;
            *(uint2*)(out + (size_t)row * H + c0) = make_uint2(f2bf2(v0, v1), f2bf2(v2, v3));
        }
    }
}

// ---------------- fused GIN2: mmA (s2 from global, relu) -> LDS -> mmB -> BN -> x2 (in-place) ----------------
__global__ __launch_bounds__(256) void k_gin2(
    const unsigned short* __restrict__ xin, const short8v* __restrict__ wpA,
    const float* __restrict__ biasA, const short8v* __restrict__ wpB,
    const float* __restrict__ biasB,
    const float* __restrict__ bn_g, const float* __restrict__ bn_b,
    const float* __restrict__ bn_rm, const float* __restrict__ bn_rv,
    unsigned short* __restrict__ out, int nN) {
    __shared__ unsigned short As[H * H];  // 32 KB swizzled bf16 tile (hA2)
    __shared__ float sBa[H], sBb[H], sS[H], sH2[H];
    const int t = threadIdx.x;

    if (t < H) {
        sBa[t] = biasA[t];
        sBb[t] = biasB[t];
        float s = bn_g[t] * rsqrtf(bn_rv[t] + 1e-5f);
        sS[t] = s;
        sH2[t] = bn_b[t] - bn_rm[t] * s;
    }
    __syncthreads();

    const int lane = t & 63;
    const int wave = t >> 6;
    const int rowbase = blockIdx.x * 128 + wave * 32;
    const int lrow = lane & 15;
    const int lhi = lane >> 4;

    f32x4 acc[2][8];
#pragma unroll
    for (int rr = 0; rr < 2; ++rr)
#pragma unroll
        for (int c = 0; c < 8; ++c) acc[rr][c] = (f32x4){0.f, 0.f, 0.f, 0.f};

    // phase 1: hA2 = relu(s2 @ W2a + b2a), xf from global
#pragma unroll
    for (int kb = 0; kb < 4; ++kb) {
        short8v xf[2];
#pragma unroll
        for (int rr = 0; rr < 2; ++rr) {
            int row = rowbase + rr * 16 + lrow;
            row = row < nN ? row : nN - 1;
            xf[rr] = *(const short8v*)(xin + (size_t)row * H + kb * 32 + lhi * 8);
        }
#pragma unroll
        for (int c16 = 0; c16 < 8; ++c16) {
            short8v wf = wpA[(kb * 8 + c16) * 64 + lane];
            acc[0][c16] = __builtin_amdgcn_mfma_f32_16x16x32_bf16(wf, xf[0], acc[0][c16], 0, 0, 0);
            acc[1][c16] = __builtin_amdgcn_mfma_f32_16x16x32_bf16(wf, xf[1], acc[1][c16], 0, 0, 0);
        }
    }

    // epilogue 1 -> swizzled LDS (hA2)
#pragma unroll
    for (int c16 = 0; c16 < 8; ++c16) {
        const int c0 = c16 * 16 + lhi * 4;
        float b0 = sBa[c0], b1 = sBa[c0 + 1], b2 = sBa[c0 + 2], b3 = sBa[c0 + 3];
#pragma unroll
        for (int rr = 0; rr < 2; ++rr) {
            int rl = wave * 32 + rr * 16 + lrow;
            float v0 = fmaxf(acc[rr][c16][0] + b0, 0.f);
            float v1 = fmaxf(acc[rr][c16][1] + b1, 0.f);
            float v2 = fmaxf(acc[rr][c16][2] + b2, 0.f);
            float v3 = fmaxf(acc[rr][c16][3] + b3, 0.f);
            int idx = rl * H + c0;
            *(uint2*)(As + (idx ^ swzmask(rl))) = make_uint2(f2bf2(v0, v1), f2bf2(v2, v3));
        }
    }
    __syncthreads();

    // phase 2: x2 = BN(relu(hA2 @ W2b + b2b)), xf from LDS
#pragma unroll
    for (int rr = 0; rr < 2; ++rr)
#pragma unroll
        for (int c = 0; c < 8; ++c) acc[rr][c] = (f32x4){0.f, 0.f, 0.f, 0.f};

#pragma unroll
    for (int kb = 0; kb < 4; ++kb) {
        short8v xf[2];
#pragma unroll
        for (int rr = 0; rr < 2; ++rr) {
            int rl = wave * 32 + rr * 16 + lrow;
            int idx = rl * H + kb * 32 + lhi * 8;
            xf[rr] = *(const short8v*)(As + (idx ^ swzmask(rl)));
        }
#pragma unroll
        for (int c16 = 0; c16 < 8; ++c16) {
            short8v wf = wpB[(kb * 8 + c16) * 64 + lane];
            acc[0][c16] = __builtin_amdgcn_mfma_f32_16x16x32_bf16(wf, xf[0], acc[0][c16], 0, 0, 0);
            acc[1][c16] = __builtin_amdgcn_mfma_f32_16x16x32_bf16(wf, xf[1], acc[1][c16], 0, 0, 0);
        }
    }

#pragma unroll
    for (int c16 = 0; c16 < 8; ++c16) {
        const int c0 = c16 * 16 + lhi * 4;
        float b0 = sBb[c0], b1 = sBb[c0 + 1], b2 = sBb[c0 + 2], b3 = sBb[c0 + 3];
        float s0 = sS[c0], s1 = sS[c0 + 1], s2 = sS[c0 + 2], s3 = sS[c0 + 3];
        float h0 = sH2[c0], h1 = sH2[c0 + 1], h2 = sH2[c0 + 2], h3 = sH2[c0 + 3];
#pragma unroll
        for (int rr = 0; rr < 2; ++rr) {
            int row = rowbase + rr * 16 + lrow;
            if (row >= nN) continue;
            float v0 = fmaxf(acc[rr][c16][0] + b0, 0.f) * s0 + h0;
            float v1 = fmaxf(acc[rr][c16][1] + b1, 0.f) * s1 + h1;
            float v2 = fmaxf(acc[rr][c16][2] + b2, 0.f) * s2 + h2;
            float v3 = fmaxf(acc[rr][c16][3] + b3, 0.f) * s3 + h3;
            *(uint2*)(out + (size_t)row * H + c0) = make_uint2(f2bf2(v0, v1), f2bf2(v2, v3));
        }
    }
}

// ---------------- one block per graph (256 thr): pools + x0g/x1g/x2g + classifier ----------------
__global__ __launch_bounds__(256) void k_graph(
    const float* __restrict__ pos,
    const unsigned short* __restrict__ x1, const unsigned short* __restrict__ x2,
    const int* __restrict__ browptr,
    const float* __restrict__ Wf1, const float* __restrict__ bf1,
    const float* __restrict__ f1g, const float* __restrict__ f1b,
    const float* __restrict__ f1rm, const float* __restrict__ f1rv,
    const float* __restrict__ Wf2T, const float* __restrict__ bf2,
    const float* __restrict__ f2g, const float* __restrict__ f2b,
    const float* __restrict__ f2rm, const float* __restrict__ f2rv,
    const float* __restrict__ Wc1T, const float* __restrict__ bc1,
    const float* __restrict__ gc, const float* __restrict__ bec,
    const float* __restrict__ rmc, const float* __restrict__ rvc,
    const float* __restrict__ ap,
    const float* __restrict__ Wc2, const float* __restrict__ bc2,
    float* __restrict__ out) {
    __shared__ float redx[256], redy[256];
    __shared__ float part1[4][16][8], part2[4][16][8];
    __shared__ float row[H];
    __shared__ float hbuf[HC];
    const int gi = blockIdx.x, t = threadIdx.x;
    const int r0 = browptr[gi], r1 = browptr[gi + 1];

    // pos pool (256-way)
    float ax = 0.f, ay = 0.f;
    for (int r = r0 + t; r < r1; r += 256) {
        float2 p = ((const float2*)pos)[r];
        ax += p.x; ay += p.y;
    }
    redx[t] = ax; redy[t] = ay;
    __syncthreads();
    for (int off = 128; off; off >>= 1) {
        if (t < off) { redx[t] += redx[t + off]; redy[t] += redy[t + off]; }
        __syncthreads();
    }
    const float px = redx[0], py = redy[0];

    // x1/x2 pools: 16 col-chunks x 16 row-lanes, uint4 loads
    {
        const int c = t & 15, l = t >> 4;
        float a1[8] = {0, 0, 0, 0, 0, 0, 0, 0};
        float a2[8] = {0, 0, 0, 0, 0, 0, 0, 0};
        for (int r = r0 + l; r < r1; r += 16) {
            unpack_add8(*(const uint4*)(x1 + (size_t)r * H + c * 8), a1);
            unpack_add8(*(const uint4*)(x2 + (size_t)r * H + c * 8), a2);
        }
#pragma unroll
        for (int k = 0; k < 8; ++k) {
            a1[k] += __shfl_xor(a1[k], 16); a1[k] += __shfl_xor(a1[k], 32);
            a2[k] += __shfl_xor(a2[k], 16); a2[k] += __shfl_xor(a2[k], 32);
        }
        const int wv = t >> 6, lane = t & 63;
        if (lane < 16) {
#pragma unroll
            for (int k = 0; k < 8; ++k) {
                part1[wv][lane][k] = a1[k];
                part2[wv][lane][k] = a2[k];
            }
        }
    }
    __syncthreads();

    float x0 = 0.f, p1 = 0.f, p2 = 0.f, s2v = 0.f;
    if (t < H) {
        const int cc = t >> 3, e = t & 7;
        p1 = part1[0][cc][e] + part1[1][cc][e] + part1[2][cc][e] + part1[3][cc][e];
        p2 = part2[0][cc][e] + part2[1][cc][e] + part2[2][cc][e] + part2[3][cc][e];
        float a0 = fmaxf(bf1[t] + px * Wf1[t] + py * Wf1[H + t], 0.f);
        float s1v = f1g[t] * rsqrtf(f1rv[t] + 1e-5f);
        x0 = (a0 - f1rm[t]) * s1v + f1b[t];
        s2v = f2g[t] * rsqrtf(f2rv[t] + 1e-5f);
        row[t] = p1 + x0;
    }
    __syncthreads();

    float x1gv = 0.f;
    if (t < H) {
        float a = bf2[t];
        const float4* wt = (const float4*)(Wf2T + t * H);
#pragma unroll 8
        for (int j4 = 0; j4 < 32; ++j4) {
            float4 w = wt[j4];
            a += row[j4 * 4] * w.x + row[j4 * 4 + 1] * w.y + row[j4 * 4 + 2] * w.z + row[j4 * 4 + 3] * w.w;
        }
        x1gv = (fmaxf(a, 0.f) - f2rm[t]) * s2v + f2b[t];
    }
    __syncthreads();
    if (t < H) row[t] = p2 + x0 + x1gv;
    __syncthreads();

    float x2gv = 0.f;
    if (t < H) {
        float a = bf2[t];
        const float4* wt = (const float4*)(Wf2T + t * H);
#pragma unroll 8
        for (int j4 = 0; j4 < 32; ++j4) {
            float4 w = wt[j4];
            a += row[j4 * 4] * w.x + row[j4 * 4 + 1] * w.y + row[j4 * 4 + 2] * w.z + row[j4 * 4 + 3] * w.w;
        }
        x2gv = (fmaxf(a, 0.f) - f2rm[t]) * s2v + f2b[t];
    }
    __syncthreads();
    if (t < H) row[t] = x2gv;
    __syncthreads();

    if (t < HC) {
        float c = bc1[t];
        const float4* wt = (const float4*)(Wc1T + t * H);
#pragma unroll 8
        for (int j4 = 0; j4 < 32; ++j4) {
            float4 w = wt[j4];
            c += row[j4 * 4] * w.x + row[j4 * 4 + 1] * w.y + row[j4 * 4 + 2] * w.z + row[j4 * 4 + 3] * w.w;
        }
        float sc = gc[t] * rsqrtf(rvc[t] + 1e-5f);
        c = (c - rmc[t]) * sc + bec[t];
        float al = ap[0];
        hbuf[t] = c > 0.f ? c : al * c;
    }
    __syncthreads();
    if (t < NOUT) {
        float c = bc2[t];
        for (int j = 0; j < HC; ++j) c += hbuf[j] * Wc2[j * NOUT + t];
        out[gi * NOUT + t] = c;
    }
}

extern "C" void kernel_launch(void* const* d_in, const int* in_sizes, int n_in,
                              void* d_out, int out_size, void* d_ws, size_t ws_size,
                              hipStream_t stream) {
    const int N = kN, E = kE, G = kG;
    const float* pos = (const float*)d_in[0];
    const int* ei    = (const int*)d_in[1];
    const int* batch = (const int*)d_in[2];
    const float* W1a = (const float*)d_in[3];
    const float* b1a = (const float*)d_in[4];
    const float* W1b = (const float*)d_in[5];
    const float* b1b = (const float*)d_in[6];
    const float* n1g = (const float*)d_in[7];
    const float* n1b = (const float*)d_in[8];
    const float* n1rm = (const float*)d_in[9];
    const float* n1rv = (const float*)d_in[10];
    const float* W2a = (const float*)d_in[11];
    const float* b2a = (const float*)d_in[12];
    const float* W2b = (const float*)d_in[13];
    const float* b2b = (const float*)d_in[14];
    const float* n2g = (const float*)d_in[15];
    const float* n2b = (const float*)d_in[16];
    const float* n2rm = (const float*)d_in[17];
    const float* n2rv = (const float*)d_in[18];
    const float* Wf1 = (const float*)d_in[19];
    const float* bf1 = (const float*)d_in[20];
    const float* f1g = (const float*)d_in[21];
    const float* f1b = (const float*)d_in[22];
    const float* f1rm = (const float*)d_in[23];
    const float* f1rv = (const float*)d_in[24];
    const float* Wf2 = (const float*)d_in[25];
    const float* bf2 = (const float*)d_in[26];
    const float* f2g = (const float*)d_in[27];
    const float* f2b = (const float*)d_in[28];
    const float* f2rm = (const float*)d_in[29];
    const float* f2rv = (const float*)d_in[30];
    const float* Wc1 = (const float*)d_in[31];
    const float* bc1 = (const float*)d_in[32];
    const float* gc  = (const float*)d_in[33];
    const float* bec = (const float*)d_in[34];
    const float* rmc = (const float*)d_in[35];
    const float* rvc = (const float*)d_in[36];
    const float* ap  = (const float*)d_in[37];
    const float* Wc2 = (const float*)d_in[38];
    const float* bc2 = (const float*)d_in[39];
    float* out = (float*)d_out;

    // ---- workspace layout ----
    unsigned short* bx1 = (unsigned short*)d_ws;        // N*H bf16 (x1)
    unsigned short* bx2 = bx1 + (size_t)N * H;          // N*H bf16 (s2 -> x2 in-place)
    unsigned short* wp  = bx2 + (size_t)N * H;          // 3*16384
    float* wf2t  = (float*)(wp + 3 * 16384);            // 16384
    float* wc1t  = wf2t + 16384;                        // 8192
    int* deg     = (int*)(wc1t + 8192);                 // N (reused as cursor)
    int* rowptr  = deg + N;                             // N+1
    int* browptr = rowptr + N + 1;                      // G+1
    int* partial = browptr + G + 1;                     // 1024
    int* eidx    = partial + 1024;                      // E

    const short8v* wp1 = (const short8v*)wp;
    const short8v* wp2 = (const short8v*)(wp + 16384);
    const short8v* wp3 = (const short8v*)(wp + 32768);

    const int* src  = ei;
    const int* dstp = ei + E;
    const int nb = (N + 1023) / 1024;  // 98

    // 1. setup: zero deg + repack W + browptr + W transposes
    k_setup<<<150, 256, 0, stream>>>(deg, W1b, W2a, W2b, wp, batch, browptr,
                                     Wf2, wf2t, Wc1, wc1t);
    // 2-5. CSR build (by dst)
    k_hist<<<(E + 255) / 256, 256, 0, stream>>>(dstp, deg, E);
    k_scan_p1<<<nb, 256, 0, stream>>>(deg, partial, N);
    k_scan_p3<<<nb, 256, 0, stream>>>(deg, partial, rowptr, deg, N, nb);
    k_scatter<<<(E + 255) / 256, 256, 0, stream>>>(src, dstp, deg, eidx, E);

    const int mmBlocks = (N + 127) / 128;

    // 6. GIN1 (pos gather fused, 2-lane edge split + 2-edge MLP)
    k_gin1<<<mmBlocks, 256, 0, stream>>>(pos, rowptr, eidx, W1a, b1a, wp1, b1b,
                                         n1g, n1b, n1rm, n1rv, bx1, N);
    // 7. s2 = x1 + gather(x1) -> bx2 (4/2-edge MLP batching)
    k_gather_add<<<(N * 16 + 255) / 256, 256, 0, stream>>>(rowptr, eidx, bx1, bx2, N);
    // 8. GIN2 (s2 from global, in-place -> x2)
    k_gin2<<<mmBlocks, 256, 0, stream>>>(bx2, wp2, b2a, wp3, b2b,
                                         n2g, n2b, n2rm, n2rv, bx2, N);
    // 9. all graph-level work + classifier
    k_graph<<<G, 256, 0, stream>>>(pos, bx1, bx2, browptr,
                                   Wf1, bf1, f1g, f1b, f1rm, f1rv,
                                   wf2t, bf2, f2g, f2b, f2rm, f2rv,
                                   wc1t, bc1, gc, bec, rmc, rvc, ap, Wc2, bc2, out);
}